// Round 15
// baseline (386.457 us; speedup 1.0000x reference)
//
#include <hip/hip_runtime.h>

typedef __bf16 bf16;
typedef __bf16 bf16x8 __attribute__((ext_vector_type(8)));
typedef __bf16 bf16x4 __attribute__((ext_vector_type(4)));
typedef float f32x4 __attribute__((ext_vector_type(4)));

#define MFMA16(a, b, c) __builtin_amdgcn_mfma_f32_16x16x32_bf16(a, b, c, 0, 0, 0)

// Problem constants
#define Bq 2
#define Sq 2048
#define Eq 2048
#define Hq 16
#define Dq 128
#define N3E 6144

// softmax scale folded into Q at the GEMM epilogue: (1/sqrt(128))*log2(e)
#define KSC (0.08838834764831845f * 1.4426950408889634f)

#define GLOAD_LDS16(gp, lp) \
  __builtin_amdgcn_global_load_lds( \
      (const __attribute__((address_space(1))) void*)(gp), \
      (__attribute__((address_space(3))) void*)(lp), 16, 0, 0)

__device__ __forceinline__ bf16 f2bf(float f) {
  unsigned u = __builtin_bit_cast(unsigned, f);
  u += 0x7FFFu + ((u >> 16) & 1u);
  unsigned short h = (unsigned short)(u >> 16);
  return __builtin_bit_cast(bf16, h);
}
__device__ __forceinline__ float bf2f(bf16 b) {
  unsigned short h = __builtin_bit_cast(unsigned short, b);
  return __builtin_bit_cast(float, (unsigned)h << 16);
}

// ---------------------------------------------------------------------------
// Kernel 0 (fused prep): blocks [0,2048) convert x (16 elems/thread);
// [2048,5120) transpose W; [5120,5632) RoPE table.
// ---------------------------------------------------------------------------
__global__ __launch_bounds__(256) void prep(const float* __restrict__ x,
                                            bf16* __restrict__ xb,
                                            const float* __restrict__ w,
                                            bf16* __restrict__ wt,
                                            float2* __restrict__ tbl) {
  __shared__ __align__(16) bf16 T[64][72];
  const int tid = threadIdx.x;
  const int bidx = blockIdx.x;

  if (bidx < 2048) {
    const size_t i = ((size_t)bidx * 256 + tid) * 16;
#pragma unroll
    for (int hh = 0; hh < 2; ++hh) {
      float4 a = *(const float4*)(x + i + hh * 8);
      float4 b = *(const float4*)(x + i + hh * 8 + 4);
      bf16x8 o;
      o[0] = f2bf(a.x); o[1] = f2bf(a.y); o[2] = f2bf(a.z); o[3] = f2bf(a.w);
      o[4] = f2bf(b.x); o[5] = f2bf(b.y); o[6] = f2bf(b.z); o[7] = f2bf(b.w);
      *(bf16x8*)(xb + i + hh * 8) = o;
    }
  } else if (bidx < 2048 + 3072) {
    const int b2 = bidx - 2048;
    const int kb = b2 & 31;  // 2048/64
    const int nb = b2 >> 5;  // 6144/64
    const int k0 = kb * 64, n0 = nb * 64;
    {
      const int kr = tid >> 4, nc = (tid & 15) * 4;
#pragma unroll
      for (int p = 0; p < 4; ++p) {
        const int k = kr + p * 16;
        float4 v = *(const float4*)(w + (size_t)(k0 + k) * N3E + n0 + nc);
        T[nc + 0][k] = f2bf(v.x);
        T[nc + 1][k] = f2bf(v.y);
        T[nc + 2][k] = f2bf(v.z);
        T[nc + 3][k] = f2bf(v.w);
      }
    }
    __syncthreads();
#pragma unroll
    for (int q = 0; q < 2; ++q) {
      const int id = q * 256 + tid;
      const int n = id >> 3, ch = id & 7;
      bf16x8 v = *(const bf16x8*)&T[n][ch * 8];
      *(bf16x8*)(wt + (size_t)(n0 + n) * Eq + k0 + ch * 8) = v;
    }
  } else {
    const int i = (bidx - 5120) * 256 + tid;  // 0 .. Sq*64-1
    const int s = i >> 6, d = i & 63;
    const float freq = __expf(-(float)d * 0.14391157f);  // ln(10000)/64
    const float ang = (float)s * freq;
    float sv, cv;
    __sincosf(ang, &sv, &cv);
    tbl[i] = make_float2(cv, sv);
  }
}

// ---------------------------------------------------------------------------
// Kernel 1: qkv = xb @ wt^T. R1 structure + R13 Q-scale fold + R14 m-fastest
// XCD swizzle (FETCH 313->217 MB confirmed; dur ~122.5 — structural ceiling
// of the m97-class 2-barrier loop; book closed).
// ---------------------------------------------------------------------------
__global__ __launch_bounds__(512, 2) void gemm_qkv(
    const bf16* __restrict__ xb, const bf16* __restrict__ wt,
    const float2* __restrict__ tbl, bf16* __restrict__ qws,
    bf16* __restrict__ kws, bf16* __restrict__ vtws) {
  __shared__ __align__(16) bf16 LDS[3 * 24576];

  const int tid = threadIdx.x;
  const int lane = tid & 63, wv = tid >> 6;
  const int q4 = lane >> 4, c = lane & 15;
  const int wm = (wv >> 2) * 64;
  const int wn = (wv & 3) * 64;
  const int cx = c & 7;

  const int bid = blockIdx.x;
  const int wg = (bid & 7) * 96 + (bid >> 3);
  const int m0 = (wg & 31) * 128;   // m-fastest within each XCD chunk
  const int n0 = (wg >> 5) * 256;   // 3 consecutive n-panels per XCD

  f32x4 acc[4][4];
#pragma unroll
  for (int i = 0; i < 4; ++i)
#pragma unroll
    for (int j = 0; j < 4; ++j) acc[i][j] = {0.f, 0.f, 0.f, 0.f};

  const int NT = Eq / 64;

  auto stage = [&](int t, int st) {
    bf16* ab = LDS + st * 24576;
    bf16* bb = ab + 8192;
    const int k0 = t * 64;
#pragma unroll
    for (int it = 0; it < 2; ++it) {
      const int slot = it * 512 + tid;
      const int row = slot >> 3, kch = slot & 7;
      const int kcs = kch ^ (row & 7);
      GLOAD_LDS16(xb + (size_t)(m0 + row) * Eq + k0 + kcs * 8, ab + slot * 8);
    }
#pragma unroll
    for (int it = 0; it < 4; ++it) {
      const int slot = it * 512 + tid;
      const int row = slot >> 3, kch = slot & 7;
      const int kcs = kch ^ (row & 7);
      GLOAD_LDS16(wt + (size_t)(n0 + row) * Eq + k0 + kcs * 8, bb + slot * 8);
    }
  };

  stage(0, 0);
  stage(1, 1);
  asm volatile("s_waitcnt vmcnt(6)" ::: "memory");
  __builtin_amdgcn_s_barrier();

  int stC = 0;
#pragma unroll 1
  for (int t = 0; t < NT; ++t) {
    if (t + 2 < NT) {
      int ss = stC + 2;
      if (ss >= 3) ss -= 3;
      stage(t + 2, ss);
    }
    const bf16* A = LDS + stC * 24576;
    const bf16* Bb = A + 8192;
#pragma unroll
    for (int kk = 0; kk < 64; kk += 32) {
      const int bch = kk >> 3;
      bf16x8 af[4], bfr[4];
#pragma unroll
      for (int i = 0; i < 4; ++i)
        af[i] = *(const bf16x8*)
            &A[(wm + i * 16 + c) * 64 + ((bch + q4) ^ cx) * 8];
#pragma unroll
      for (int j = 0; j < 4; ++j)
        bfr[j] = *(const bf16x8*)
            &Bb[(wn + j * 16 + c) * 64 + ((bch + q4) ^ cx) * 8];
      __builtin_amdgcn_s_setprio(1);
#pragma unroll
      for (int i = 0; i < 4; ++i)
#pragma unroll
        for (int j = 0; j < 4; ++j)
          acc[i][j] = MFMA16(af[i], bfr[j], acc[i][j]);
      __builtin_amdgcn_s_setprio(0);
    }
    if (t + 1 < NT) {
      if (t + 2 < NT) asm volatile("s_waitcnt vmcnt(6)" ::: "memory");
      else            asm volatile("s_waitcnt vmcnt(0)" ::: "memory");
      __builtin_amdgcn_s_barrier();
    }
    stC = stC == 2 ? 0 : stC + 1;
  }
  __syncthreads();

  const int t3 = n0 >> 11;
  const int b = m0 >> 11;
  const int s0 = m0 & 2047;
  const int h0 = (n0 & 2047) >> 7;

  bf16* E = LDS;

  if (t3 == 2) {
#pragma unroll 1
    for (int hh = 0; hh < 2; ++hh) {
      if (((wv & 3) >> 1) == hh) {
#pragma unroll
        for (int i = 0; i < 4; ++i)
#pragma unroll
          for (int j = 0; j < 4; ++j) {
            bf16x4 pv;
            pv[0] = f2bf(acc[i][j][0]); pv[1] = f2bf(acc[i][j][1]);
            pv[2] = f2bf(acc[i][j][2]); pv[3] = f2bf(acc[i][j][3]);
            *(bf16x4*)&E[((wn & 127) + j * 16 + c) * 136 + wm + i * 16 +
                         q4 * 4] = pv;
          }
      }
      __syncthreads();
      bf16* vbase = vtws + ((size_t)(b * Hq + h0 + hh) * Dq) * Sq + s0;
#pragma unroll
      for (int p = 0; p < 4; ++p) {
        const int id = p * 512 + tid;
        const int d = id >> 4, ch = id & 15;
        bf16x8 v = *(const bf16x8*)&E[d * 136 + ch * 8];
        *(bf16x8*)&vbase[(size_t)d * Sq + ch * 8] = v;
      }
      __syncthreads();
    }
  } else {
    const float qs = (t3 == 0) ? (float)KSC : 1.0f;  // fold scale into Q
#pragma unroll 1
    for (int hh = 0; hh < 2; ++hh) {
      if (((wv & 3) >> 1) == hh) {
#pragma unroll
        for (int i = 0; i < 4; ++i)
#pragma unroll
          for (int j = 0; j < 4; ++j)
#pragma unroll
            for (int rr = 0; rr < 4; ++rr)
              E[(wm + i * 16 + q4 * 4 + rr) * 136 + (wn & 127) + j * 16 + c] =
                  f2bf(acc[i][j][rr]);
      }
      __syncthreads();
      bf16* hd = ((t3 == 0) ? qws : kws) +
                 ((size_t)(b * Hq + h0 + hh) * Sq + s0) * Dq;
#pragma unroll
      for (int p = 0; p < 2; ++p) {
        const int row = p * 64 + (tid >> 3);
        const int dlow = (tid & 7) * 8;
        const int s = s0 + row;
        bf16x8 lo = *(const bf16x8*)&E[row * 136 + dlow];
        bf16x8 hi = *(const bf16x8*)&E[row * 136 + 64 + dlow];
        const float2* tb = tbl + (size_t)s * 64 + dlow;
        bf16x8 olo, ohi;
#pragma unroll
        for (int e = 0; e < 8; ++e) {
          const float cv = tb[e].x, sv = tb[e].y;
          const float x1 = bf2f(lo[e]), x2 = bf2f(hi[e]);
          olo[e] = f2bf((x1 * cv - x2 * sv) * qs);
          ohi[e] = f2bf((x2 * cv + x1 * sv) * qs);
        }
        *(bf16x8*)&hd[(size_t)row * Dq + dlow] = olo;
        *(bf16x8*)&hd[(size_t)row * Dq + 64 + dlow] = ohi;
      }
      __syncthreads();
    }
  }
}

// ---------------------------------------------------------------------------
// R9 static split-K schedule + R13 pre-scaled scores. ROUND-15 change:
// SINGLE-BUFFERED K/V -> LDS 75->41.25 KB -> __launch_bounds__(256,3) = 3
// blocks/CU (12 waves, +50% TLP). attn is latency-bound on the per-chunk
// serial chain (MfmaUtil 11%, VALUBusy 27%, Occ 13% — no pipe saturated);
// the dbuf prefetch overlap is traded for cross-block hiding. Stage is
// issued AFTER the post-compute barrier (WAR-safe: no wave still reads
// when the DMA writes land); vmcnt(0)+barrier before compute (RAW-safe).
// ---------------------------------------------------------------------------
__device__ const int dSQT0[16] = {15,15, 7,14,14, 6,13,13,12,12,11,11, 8,10,10, 9};
__device__ const int dSSP0[16] = { 0, 1, 2, 0, 1, 2, 0, 1, 0, 1, 0, 1, 0, 0, 1, 0};
__device__ const int dSQT1[16] = {-1,-1,-1,-1,-1,-1,-1,-1, 0, 1, 2, 3, 5, 8, 4, 9};
__device__ const int dSSP1[16] = { 0, 0, 0, 0, 0, 0, 0, 0, 2, 2, 2, 2, 2, 1, 2, 1};
__device__ const int dZP[16]   = { 9, 2, 1,13,15,12,14,11,10, 0, 8, 7, 5, 3, 6, 4};

__global__ __launch_bounds__(256, 3) void attn_kernel(
    const bf16* __restrict__ qws, const bf16* __restrict__ kws,
    const bf16* __restrict__ vtws, float* __restrict__ out,
    float* __restrict__ opart, float* __restrict__ ml) {
  __shared__ __align__(16) bf16 Kld[8192];
  __shared__ __align__(16) bf16 Vld[8192];
  __shared__ __align__(16) bf16 Plds[4][16][72];

  const int tid = threadIdx.x, lane = tid & 63, wave = tid >> 6;
  const int q4 = lane >> 4, c = lane & 15;
  const int h = blockIdx.y, b = blockIdx.z;
  const int sidx = (b == 0) ? blockIdx.x : dZP[blockIdx.x];

  const size_t bh = (size_t)(b * Hq + h);
  const bf16* qbase = qws + bh * Sq * Dq;
  const bf16* kbase = kws + bh * Sq * Dq;
  const bf16* vbase = vtws + bh * Dq * Sq;

  // stage chunk kb into the single K/V buffers (8 gloads/thread)
  auto stageKV = [&](int kb) {
    const int koff = kb * 64;
#pragma unroll
    for (int it = 0; it < 4; ++it) {
      const int slot = it * 256 + tid;
      GLOAD_LDS16(kbase + (size_t)(koff + (slot & 63)) * Dq + (slot >> 6) * 8,
                  &Kld[slot * 8]);
      GLOAD_LDS16(vbase + (size_t)(slot & 127) * Sq + koff + (slot >> 7) * 8,
                  &Vld[slot * 8]);
    }
  };

#pragma unroll 1
  for (int seg = 0; seg < 2; ++seg) {
    const int qt = (seg == 0) ? dSQT0[sidx] : dSQT1[sidx];
    if (qt < 0) break;
    const int sp = (seg == 0) ? dSSP0[sidx] : dSSP1[sidx];
    const bool split = (sp != 2);
    const int c0 = split ? sp * (qt + 1) : 0;
    const int c1 = split ? c0 + (qt + 1) : 2 * qt + 2;
    const int q0 = qt * 128 + wave * 32;

    bf16x8 qf[2][4];
#pragma unroll
    for (int g = 0; g < 2; ++g)
#pragma unroll
      for (int ks = 0; ks < 4; ++ks)
        qf[g][ks] = *(const bf16x8*)
            &qbase[(size_t)(q0 + g * 16 + c) * Dq + ks * 32 + q4 * 8];

    f32x4 Ot[2][8];
    float m_i[2], l_i[2];
#pragma unroll
    for (int g = 0; g < 2; ++g) {
#pragma unroll
      for (int dj = 0; dj < 8; ++dj) Ot[g][dj] = {0.f, 0.f, 0.f, 0.f};
      m_i[g] = -1e30f; l_i[g] = 0.f;
    }

    // Cross-segment handoff: all waves done with previous segment's buffers.
    __syncthreads();
    stageKV(c0);

    for (int kb = c0; kb < c1; ++kb) {
      // RAW: drain this chunk's stage (own loads), then block-wide barrier.
      asm volatile("s_waitcnt vmcnt(0)" ::: "memory");
      __builtin_amdgcn_s_barrier();
      const bool masked = (kb >= 2 * qt);
#pragma unroll
      for (int g = 0; g < 2; ++g) {
        const int qg = q0 + g * 16 + c;
        f32x4 st[4];
#pragma unroll
        for (int j8 = 0; j8 < 4; ++j8) st[j8] = {0.f, 0.f, 0.f, 0.f};
        __builtin_amdgcn_s_setprio(1);
#pragma unroll
        for (int ks = 0; ks < 4; ++ks) {
          const bf16x8 qv = qf[g][ks];
#pragma unroll
          for (int j8 = 0; j8 < 4; ++j8) {
            const bf16x8 kv = *(const bf16x8*)
                &Kld[((ks * 4 + q4) * 64 + j8 * 16 + c) * 8];
            st[j8] = MFMA16(kv, qv, st[j8]);
          }
        }
        __builtin_amdgcn_s_setprio(0);
        if (masked) {
          const int kb64 = kb * 64 + q4 * 4;
#pragma unroll
          for (int j8 = 0; j8 < 4; ++j8)
#pragma unroll
            for (int rr = 0; rr < 4; ++rr)
              if (kb64 + j8 * 16 + rr > qg) st[j8][rr] = -1e30f;
        }
        float mloc = -1e30f;
#pragma unroll
        for (int j8 = 0; j8 < 4; ++j8)
#pragma unroll
          for (int rr = 0; rr < 4; ++rr) mloc = fmaxf(mloc, st[j8][rr]);
        mloc = fmaxf(mloc, __shfl_xor(mloc, 16, 64));
        mloc = fmaxf(mloc, __shfl_xor(mloc, 32, 64));
        float mn = m_i[g];
        if (__any(mloc > mn)) {
          mn = fmaxf(mn, mloc);
          const float alpha = exp2f(m_i[g] - mn);  // scores pre-scaled
          m_i[g] = mn;
          l_i[g] *= alpha;
#pragma unroll
          for (int dj = 0; dj < 8; ++dj) Ot[g][dj] *= alpha;
        }
        float ssum = 0.f;
#pragma unroll
        for (int j8 = 0; j8 < 4; ++j8)
#pragma unroll
          for (int rr = 0; rr < 4; ++rr) {
            const float p = exp2f(st[j8][rr] - mn);  // scores pre-scaled
            st[j8][rr] = p;
            ssum += p;
          }
        ssum += __shfl_xor(ssum, 16, 64);
        ssum += __shfl_xor(ssum, 32, 64);
        l_i[g] += ssum;
#pragma unroll
        for (int j8 = 0; j8 < 4; ++j8) {
          bf16x4 pk;
          pk[0] = f2bf(st[j8][0]); pk[1] = f2bf(st[j8][1]);
          pk[2] = f2bf(st[j8][2]); pk[3] = f2bf(st[j8][3]);
          *(bf16x4*)&Plds[wave][c][j8 * 16 + q4 * 4] = pk;
        }
        __builtin_amdgcn_s_setprio(1);
#pragma unroll
        for (int ks = 0; ks < 2; ++ks) {
          const bf16x8 pv = *(const bf16x8*)&Plds[wave][c][ks * 32 + q4 * 8];
#pragma unroll
          for (int dj = 0; dj < 8; ++dj) {
            const bf16x8 vv = *(const bf16x8*)
                &Vld[((ks * 4 + q4) * 128 + dj * 16 + c) * 8];
            Ot[g][dj] = MFMA16(vv, pv, Ot[g][dj]);
          }
        }
        __builtin_amdgcn_s_setprio(0);
      }
      // WAR: all waves done reading K/V before next stage overwrites.
      __builtin_amdgcn_s_barrier();
      if (kb + 1 < c1) stageKV(kb + 1);
    }

    if (!split) {
#pragma unroll
      for (int g = 0; g < 2; ++g) {
        const float inv = 1.0f / l_i[g];
        float* orow = out + ((size_t)b * Sq + q0 + g * 16 + c) * Eq + h * Dq;
#pragma unroll
        for (int dj = 0; dj < 8; ++dj) {
          float4 o;
          o.x = Ot[g][dj][0] * inv; o.y = Ot[g][dj][1] * inv;
          o.z = Ot[g][dj][2] * inv; o.w = Ot[g][dj][3] * inv;
          *(float4*)&orow[dj * 16 + q4 * 4] = o;
        }
      }
    } else {
      const int tix = (((b * Hq + h) * 8) + (qt - 8)) * 2 + sp;
#pragma unroll
      for (int g = 0; g < 2; ++g) {
        const int wrow = wave * 32 + g * 16 + c;
        float* prow = opart + ((size_t)tix * 128 + wrow) * 128;
#pragma unroll
        for (int dj = 0; dj < 8; ++dj) {
          float4 o;
          o.x = Ot[g][dj][0]; o.y = Ot[g][dj][1];
          o.z = Ot[g][dj][2]; o.w = Ot[g][dj][3];
          *(float4*)&prow[dj * 16 + q4 * 4] = o;
        }
        if (q4 == 0) {
          ml[((size_t)tix * 128 + wrow) * 2 + 0] = m_i[g];
          ml[((size_t)tix * 128 + wrow) * 2 + 1] = l_i[g];
        }
      }
    }
  }
}

// ---------------------------------------------------------------------------
// Kernel 4: combine the two split-K halves for qt>=8 tiles (verified).
// ---------------------------------------------------------------------------
__global__ __launch_bounds__(256) void attn_combine(
    const float* __restrict__ opart, const float* __restrict__ ml,
    float* __restrict__ out) {
  const int tile = blockIdx.x;
  const int qt = (tile & 7) + 8;
  const int hb = tile >> 3;
  const int h = hb & 15, b = hb >> 4;
  const int tid = threadIdx.x;
  const int r = tid >> 1;
  const int d0 = (tid & 1) * 64;
  const int t0 = tile * 2, t1 = t0 + 1;

  const float m0 = ml[((size_t)t0 * 128 + r) * 2 + 0];
  const float l0 = ml[((size_t)t0 * 128 + r) * 2 + 1];
  const float m1 = ml[((size_t)t1 * 128 + r) * 2 + 0];
  const float l1 = ml[((size_t)t1 * 128 + r) * 2 + 1];
  const float m = fmaxf(m0, m1);
  const float w0 = exp2f(m0 - m);
  const float w1 = exp2f(m1 - m);
  const float inv = 1.0f / (l0 * w0 + l1 * w1);
  const float s0 = w0 * inv, s1 = w1 * inv;

  const float* p0 = opart + ((size_t)t0 * 128 + r) * 128 + d0;
  const float* p1 = opart + ((size_t)t1 * 128 + r) * 128 + d0;
  float* orow = out + ((size_t)(b * Sq + qt * 128 + r)) * Eq + h * Dq + d0;
#pragma unroll
  for (int i = 0; i < 16; ++i) {
    float4 a = *(const float4*)&p0[i * 4];
    float4 bb = *(const float4*)&p1[i * 4];
    float4 o;
    o.x = a.x * s0 + bb.x * s1;
    o.y = a.y * s0 + bb.y * s1;
    o.z = a.z * s0 + bb.z * s1;
    o.w = a.w * s0 + bb.w * s1;
    *(float4*)&orow[i * 4] = o;
  }
}

// ---------------------------------------------------------------------------
extern "C" void kernel_launch(void* const* d_in, const int* in_sizes, int n_in,
                              void* d_out, int out_size, void* d_ws,
                              size_t ws_size, hipStream_t stream) {
  const float* x = (const float*)d_in[0];
  // d_in[1] = mask (causal tril) — implemented analytically, not read.
  const float* w = (const float*)d_in[2];
  float* out = (float*)d_out;

  const size_t nX = (size_t)Bq * Sq * Eq;         // 8,388,608
  const size_t nW = (size_t)Eq * N3E;             // 12,582,912
  const size_t perT = (size_t)Bq * Hq * Sq * Dq;  // 8,388,608

  bf16* xb = (bf16*)d_ws;
  bf16* wt = xb + nX;
  bf16* qws = wt + nW;
  bf16* kws = qws + perT;
  bf16* vtws = kws + perT;
  float2* tbl = (float2*)(vtws + perT);  // 2048*64 float2 = 1 MB
  float* wsend = (float*)(tbl + (size_t)Sq * 64);

  // Dedicated opart region (R10); fallback to aliasing if workspace small.
  const size_t nOpart = (size_t)512 * 128 * 128;      // 33.55 MB f32
  const size_t nMl = (size_t)512 * 128 * 2;           // 0.5 MB f32
  const size_t usedB = (size_t)((char*)wsend - (char*)d_ws);
  float* opart;
  if (ws_size >= usedB + (nOpart + nMl) * sizeof(float)) {
    opart = wsend;               // dedicated region (no aliasing)
  } else {
    opart = (float*)d_ws;        // fallback (aliases xb/wt)
  }
  float* ml = opart + nOpart;

  prep<<<5632, 256, 0, stream>>>(x, xb, w, wt, tbl);

  gemm_qkv<<<768, 512, 0, stream>>>(xb, wt, tbl, qws, kws, vtws);

  dim3 g3(16, 16, 2);  // 512 blocks; static split-K schedule
  attn_kernel<<<g3, 256, 0, stream>>>(qws, kws, vtws, out, opart, ml);

  attn_combine<<<256, 256, 0, stream>>>(opart, ml, out);
}

// Round 16
// 361.385 us; speedup vs baseline: 1.0694x; 1.0694x over previous
//
#include <hip/hip_runtime.h>

typedef __bf16 bf16;
typedef __bf16 bf16x8 __attribute__((ext_vector_type(8)));
typedef __bf16 bf16x4 __attribute__((ext_vector_type(4)));
typedef float f32x4 __attribute__((ext_vector_type(4)));

#define MFMA16(a, b, c) __builtin_amdgcn_mfma_f32_16x16x32_bf16(a, b, c, 0, 0, 0)

// Problem constants
#define Bq 2
#define Sq 2048
#define Eq 2048
#define Hq 16
#define Dq 128
#define N3E 6144

// softmax scale folded into Q at the GEMM epilogue: (1/sqrt(128))*log2(e)
#define KSC (0.08838834764831845f * 1.4426950408889634f)

#define GLOAD_LDS16(gp, lp) \
  __builtin_amdgcn_global_load_lds( \
      (const __attribute__((address_space(1))) void*)(gp), \
      (__attribute__((address_space(3))) void*)(lp), 16, 0, 0)

__device__ __forceinline__ bf16 f2bf(float f) {
  unsigned u = __builtin_bit_cast(unsigned, f);
  u += 0x7FFFu + ((u >> 16) & 1u);
  unsigned short h = (unsigned short)(u >> 16);
  return __builtin_bit_cast(bf16, h);
}
__device__ __forceinline__ float bf2f(bf16 b) {
  unsigned short h = __builtin_bit_cast(unsigned short, b);
  return __builtin_bit_cast(float, (unsigned)h << 16);
}

// ---------------------------------------------------------------------------
// Kernel 0 (fused prep): blocks [0,2048) convert x (16 elems/thread);
// [2048,5120) transpose W; [5120,5632) RoPE table.
// ---------------------------------------------------------------------------
__global__ __launch_bounds__(256) void prep(const float* __restrict__ x,
                                            bf16* __restrict__ xb,
                                            const float* __restrict__ w,
                                            bf16* __restrict__ wt,
                                            float2* __restrict__ tbl) {
  __shared__ __align__(16) bf16 T[64][72];
  const int tid = threadIdx.x;
  const int bidx = blockIdx.x;

  if (bidx < 2048) {
    const size_t i = ((size_t)bidx * 256 + tid) * 16;
#pragma unroll
    for (int hh = 0; hh < 2; ++hh) {
      float4 a = *(const float4*)(x + i + hh * 8);
      float4 b = *(const float4*)(x + i + hh * 8 + 4);
      bf16x8 o;
      o[0] = f2bf(a.x); o[1] = f2bf(a.y); o[2] = f2bf(a.z); o[3] = f2bf(a.w);
      o[4] = f2bf(b.x); o[5] = f2bf(b.y); o[6] = f2bf(b.z); o[7] = f2bf(b.w);
      *(bf16x8*)(xb + i + hh * 8) = o;
    }
  } else if (bidx < 2048 + 3072) {
    const int b2 = bidx - 2048;
    const int kb = b2 & 31;  // 2048/64
    const int nb = b2 >> 5;  // 6144/64
    const int k0 = kb * 64, n0 = nb * 64;
    {
      const int kr = tid >> 4, nc = (tid & 15) * 4;
#pragma unroll
      for (int p = 0; p < 4; ++p) {
        const int k = kr + p * 16;
        float4 v = *(const float4*)(w + (size_t)(k0 + k) * N3E + n0 + nc);
        T[nc + 0][k] = f2bf(v.x);
        T[nc + 1][k] = f2bf(v.y);
        T[nc + 2][k] = f2bf(v.z);
        T[nc + 3][k] = f2bf(v.w);
      }
    }
    __syncthreads();
#pragma unroll
    for (int q = 0; q < 2; ++q) {
      const int id = q * 256 + tid;
      const int n = id >> 3, ch = id & 7;
      bf16x8 v = *(const bf16x8*)&T[n][ch * 8];
      *(bf16x8*)(wt + (size_t)(n0 + n) * Eq + k0 + ch * 8) = v;
    }
  } else {
    const int i = (bidx - 5120) * 256 + tid;  // 0 .. Sq*64-1
    const int s = i >> 6, d = i & 63;
    const float freq = __expf(-(float)d * 0.14391157f);  // ln(10000)/64
    const float ang = (float)s * freq;
    float sv, cv;
    __sincosf(ang, &sv, &cv);
    tbl[i] = make_float2(cv, sv);
  }
}

// ---------------------------------------------------------------------------
// Kernel 1: qkv = xb @ wt^T. R1 structure + R13 Q-scale fold + R14 m-fastest
// XCD swizzle (FETCH 313->217 MB confirmed; ~122.5 us = structural ceiling
// of the m97-class 2-barrier loop).
// ---------------------------------------------------------------------------
__global__ __launch_bounds__(512, 2) void gemm_qkv(
    const bf16* __restrict__ xb, const bf16* __restrict__ wt,
    const float2* __restrict__ tbl, bf16* __restrict__ qws,
    bf16* __restrict__ kws, bf16* __restrict__ vtws) {
  __shared__ __align__(16) bf16 LDS[3 * 24576];

  const int tid = threadIdx.x;
  const int lane = tid & 63, wv = tid >> 6;
  const int q4 = lane >> 4, c = lane & 15;
  const int wm = (wv >> 2) * 64;
  const int wn = (wv & 3) * 64;
  const int cx = c & 7;

  const int bid = blockIdx.x;
  const int wg = (bid & 7) * 96 + (bid >> 3);
  const int m0 = (wg & 31) * 128;   // m-fastest within each XCD chunk
  const int n0 = (wg >> 5) * 256;   // 3 consecutive n-panels per XCD

  f32x4 acc[4][4];
#pragma unroll
  for (int i = 0; i < 4; ++i)
#pragma unroll
    for (int j = 0; j < 4; ++j) acc[i][j] = {0.f, 0.f, 0.f, 0.f};

  const int NT = Eq / 64;

  auto stage = [&](int t, int st) {
    bf16* ab = LDS + st * 24576;
    bf16* bb = ab + 8192;
    const int k0 = t * 64;
#pragma unroll
    for (int it = 0; it < 2; ++it) {
      const int slot = it * 512 + tid;
      const int row = slot >> 3, kch = slot & 7;
      const int kcs = kch ^ (row & 7);
      GLOAD_LDS16(xb + (size_t)(m0 + row) * Eq + k0 + kcs * 8, ab + slot * 8);
    }
#pragma unroll
    for (int it = 0; it < 4; ++it) {
      const int slot = it * 512 + tid;
      const int row = slot >> 3, kch = slot & 7;
      const int kcs = kch ^ (row & 7);
      GLOAD_LDS16(wt + (size_t)(n0 + row) * Eq + k0 + kcs * 8, bb + slot * 8);
    }
  };

  stage(0, 0);
  stage(1, 1);
  asm volatile("s_waitcnt vmcnt(6)" ::: "memory");
  __builtin_amdgcn_s_barrier();

  int stC = 0;
#pragma unroll 1
  for (int t = 0; t < NT; ++t) {
    if (t + 2 < NT) {
      int ss = stC + 2;
      if (ss >= 3) ss -= 3;
      stage(t + 2, ss);
    }
    const bf16* A = LDS + stC * 24576;
    const bf16* Bb = A + 8192;
#pragma unroll
    for (int kk = 0; kk < 64; kk += 32) {
      const int bch = kk >> 3;
      bf16x8 af[4], bfr[4];
#pragma unroll
      for (int i = 0; i < 4; ++i)
        af[i] = *(const bf16x8*)
            &A[(wm + i * 16 + c) * 64 + ((bch + q4) ^ cx) * 8];
#pragma unroll
      for (int j = 0; j < 4; ++j)
        bfr[j] = *(const bf16x8*)
            &Bb[(wn + j * 16 + c) * 64 + ((bch + q4) ^ cx) * 8];
      __builtin_amdgcn_s_setprio(1);
#pragma unroll
      for (int i = 0; i < 4; ++i)
#pragma unroll
        for (int j = 0; j < 4; ++j)
          acc[i][j] = MFMA16(af[i], bfr[j], acc[i][j]);
      __builtin_amdgcn_s_setprio(0);
    }
    if (t + 1 < NT) {
      if (t + 2 < NT) asm volatile("s_waitcnt vmcnt(6)" ::: "memory");
      else            asm volatile("s_waitcnt vmcnt(0)" ::: "memory");
      __builtin_amdgcn_s_barrier();
    }
    stC = stC == 2 ? 0 : stC + 1;
  }
  __syncthreads();

  const int t3 = n0 >> 11;
  const int b = m0 >> 11;
  const int s0 = m0 & 2047;
  const int h0 = (n0 & 2047) >> 7;

  bf16* E = LDS;

  if (t3 == 2) {
#pragma unroll 1
    for (int hh = 0; hh < 2; ++hh) {
      if (((wv & 3) >> 1) == hh) {
#pragma unroll
        for (int i = 0; i < 4; ++i)
#pragma unroll
          for (int j = 0; j < 4; ++j) {
            bf16x4 pv;
            pv[0] = f2bf(acc[i][j][0]); pv[1] = f2bf(acc[i][j][1]);
            pv[2] = f2bf(acc[i][j][2]); pv[3] = f2bf(acc[i][j][3]);
            *(bf16x4*)&E[((wn & 127) + j * 16 + c) * 136 + wm + i * 16 +
                         q4 * 4] = pv;
          }
      }
      __syncthreads();
      bf16* vbase = vtws + ((size_t)(b * Hq + h0 + hh) * Dq) * Sq + s0;
#pragma unroll
      for (int p = 0; p < 4; ++p) {
        const int id = p * 512 + tid;
        const int d = id >> 4, ch = id & 15;
        bf16x8 v = *(const bf16x8*)&E[d * 136 + ch * 8];
        *(bf16x8*)&vbase[(size_t)d * Sq + ch * 8] = v;
      }
      __syncthreads();
    }
  } else {
    const float qs = (t3 == 0) ? (float)KSC : 1.0f;  // fold scale into Q
#pragma unroll 1
    for (int hh = 0; hh < 2; ++hh) {
      if (((wv & 3) >> 1) == hh) {
#pragma unroll
        for (int i = 0; i < 4; ++i)
#pragma unroll
          for (int j = 0; j < 4; ++j)
#pragma unroll
            for (int rr = 0; rr < 4; ++rr)
              E[(wm + i * 16 + q4 * 4 + rr) * 136 + (wn & 127) + j * 16 + c] =
                  f2bf(acc[i][j][rr]);
      }
      __syncthreads();
      bf16* hd = ((t3 == 0) ? qws : kws) +
                 ((size_t)(b * Hq + h0 + hh) * Sq + s0) * Dq;
#pragma unroll
      for (int p = 0; p < 2; ++p) {
        const int row = p * 64 + (tid >> 3);
        const int dlow = (tid & 7) * 8;
        const int s = s0 + row;
        bf16x8 lo = *(const bf16x8*)&E[row * 136 + dlow];
        bf16x8 hi = *(const bf16x8*)&E[row * 136 + 64 + dlow];
        const float2* tb = tbl + (size_t)s * 64 + dlow;
        bf16x8 olo, ohi;
#pragma unroll
        for (int e = 0; e < 8; ++e) {
          const float cv = tb[e].x, sv = tb[e].y;
          const float x1 = bf2f(lo[e]), x2 = bf2f(hi[e]);
          olo[e] = f2bf((x1 * cv - x2 * sv) * qs);
          ohi[e] = f2bf((x2 * cv + x1 * sv) * qs);
        }
        *(bf16x8*)&hd[(size_t)row * Dq + dlow] = olo;
        *(bf16x8*)&hd[(size_t)row * Dq + 64 + dlow] = ohi;
      }
      __syncthreads();
    }
  }
}

// ---------------------------------------------------------------------------
// R9 static split-K schedule + R11 counted-wait loop + R13 pre-scaled
// scores. Double-buffered K/V, 2 blocks/CU — R15 proved this the optimum
// (mono-buffer + 3 blocks/CU: attn 105->128 us, exposed stage latency).
// ---------------------------------------------------------------------------
__device__ const int dSQT0[16] = {15,15, 7,14,14, 6,13,13,12,12,11,11, 8,10,10, 9};
__device__ const int dSSP0[16] = { 0, 1, 2, 0, 1, 2, 0, 1, 0, 1, 0, 1, 0, 0, 1, 0};
__device__ const int dSQT1[16] = {-1,-1,-1,-1,-1,-1,-1,-1, 0, 1, 2, 3, 5, 8, 4, 9};
__device__ const int dSSP1[16] = { 0, 0, 0, 0, 0, 0, 0, 0, 2, 2, 2, 2, 2, 1, 2, 1};
__device__ const int dZP[16]   = { 9, 2, 1,13,15,12,14,11,10, 0, 8, 7, 5, 3, 6, 4};

__global__ __launch_bounds__(256, 2) void attn_kernel(
    const bf16* __restrict__ qws, const bf16* __restrict__ kws,
    const bf16* __restrict__ vtws, float* __restrict__ out,
    float* __restrict__ opart, float* __restrict__ ml) {
  __shared__ __align__(16) bf16 Kld[2][8192];
  __shared__ __align__(16) bf16 Vld[2][8192];
  __shared__ __align__(16) bf16 Plds[4][16][72];

  const int tid = threadIdx.x, lane = tid & 63, wave = tid >> 6;
  const int q4 = lane >> 4, c = lane & 15;
  const int h = blockIdx.y, b = blockIdx.z;
  const int sidx = (b == 0) ? blockIdx.x : dZP[blockIdx.x];

  const size_t bh = (size_t)(b * Hq + h);
  const bf16* qbase = qws + bh * Sq * Dq;
  const bf16* kbase = kws + bh * Sq * Dq;
  const bf16* vbase = vtws + bh * Dq * Sq;

#pragma unroll 1
  for (int seg = 0; seg < 2; ++seg) {
    const int qt = (seg == 0) ? dSQT0[sidx] : dSQT1[sidx];
    if (qt < 0) break;
    const int sp = (seg == 0) ? dSSP0[sidx] : dSSP1[sidx];
    const bool split = (sp != 2);
    const int c0 = split ? sp * (qt + 1) : 0;
    const int c1 = split ? c0 + (qt + 1) : 2 * qt + 2;
    const int q0 = qt * 128 + wave * 32;

    bf16x8 qf[2][4];
#pragma unroll
    for (int g = 0; g < 2; ++g)
#pragma unroll
      for (int ks = 0; ks < 4; ++ks)
        qf[g][ks] = *(const bf16x8*)
            &qbase[(size_t)(q0 + g * 16 + c) * Dq + ks * 32 + q4 * 8];

    f32x4 Ot[2][8];
    float m_i[2], l_i[2];
#pragma unroll
    for (int g = 0; g < 2; ++g) {
#pragma unroll
      for (int dj = 0; dj < 8; ++dj) Ot[g][dj] = {0.f, 0.f, 0.f, 0.f};
      m_i[g] = -1e30f; l_i[g] = 0.f;
    }

    // Cross-segment LDS handoff.
    __syncthreads();
    {
      const int koff0 = c0 * 64;
#pragma unroll
      for (int it = 0; it < 4; ++it) {
        const int slot = it * 256 + tid;
        GLOAD_LDS16(
            kbase + (size_t)(koff0 + (slot & 63)) * Dq + (slot >> 6) * 8,
            &Kld[c0 & 1][slot * 8]);
        GLOAD_LDS16(
            vbase + (size_t)(slot & 127) * Sq + koff0 + (slot >> 7) * 8,
            &Vld[c0 & 1][slot * 8]);
      }
    }

    for (int kb = c0; kb < c1; ++kb) {
      const int buf = kb & 1;
      asm volatile("s_waitcnt vmcnt(0)" ::: "memory");
      __builtin_amdgcn_s_barrier();
      if (kb + 1 < c1) {
        const int nb = buf ^ 1;
        const int koff = (kb + 1) * 64;
#pragma unroll
        for (int it = 0; it < 4; ++it) {
          const int slot = it * 256 + tid;
          GLOAD_LDS16(
              kbase + (size_t)(koff + (slot & 63)) * Dq + (slot >> 6) * 8,
              &Kld[nb][slot * 8]);
          GLOAD_LDS16(
              vbase + (size_t)(slot & 127) * Sq + koff + (slot >> 7) * 8,
              &Vld[nb][slot * 8]);
        }
      }
      const bool masked = (kb >= 2 * qt);
#pragma unroll
      for (int g = 0; g < 2; ++g) {
        const int qg = q0 + g * 16 + c;
        f32x4 st[4];
#pragma unroll
        for (int j8 = 0; j8 < 4; ++j8) st[j8] = {0.f, 0.f, 0.f, 0.f};
        __builtin_amdgcn_s_setprio(1);
#pragma unroll
        for (int ks = 0; ks < 4; ++ks) {
          const bf16x8 qv = qf[g][ks];
#pragma unroll
          for (int j8 = 0; j8 < 4; ++j8) {
            const bf16x8 kv = *(const bf16x8*)
                &Kld[buf][((ks * 4 + q4) * 64 + j8 * 16 + c) * 8];
            st[j8] = MFMA16(kv, qv, st[j8]);
          }
        }
        __builtin_amdgcn_s_setprio(0);
        if (masked) {
          const int kb64 = kb * 64 + q4 * 4;
#pragma unroll
          for (int j8 = 0; j8 < 4; ++j8)
#pragma unroll
            for (int rr = 0; rr < 4; ++rr)
              if (kb64 + j8 * 16 + rr > qg) st[j8][rr] = -1e30f;
        }
        float mloc = -1e30f;
#pragma unroll
        for (int j8 = 0; j8 < 4; ++j8)
#pragma unroll
          for (int rr = 0; rr < 4; ++rr) mloc = fmaxf(mloc, st[j8][rr]);
        mloc = fmaxf(mloc, __shfl_xor(mloc, 16, 64));
        mloc = fmaxf(mloc, __shfl_xor(mloc, 32, 64));
        float mn = m_i[g];
        if (__any(mloc > mn)) {
          mn = fmaxf(mn, mloc);
          const float alpha = exp2f(m_i[g] - mn);  // scores pre-scaled
          m_i[g] = mn;
          l_i[g] *= alpha;
#pragma unroll
          for (int dj = 0; dj < 8; ++dj) Ot[g][dj] *= alpha;
        }
        float ssum = 0.f;
#pragma unroll
        for (int j8 = 0; j8 < 4; ++j8)
#pragma unroll
          for (int rr = 0; rr < 4; ++rr) {
            const float p = exp2f(st[j8][rr] - mn);  // scores pre-scaled
            st[j8][rr] = p;
            ssum += p;
          }
        ssum += __shfl_xor(ssum, 16, 64);
        ssum += __shfl_xor(ssum, 32, 64);
        l_i[g] += ssum;
#pragma unroll
        for (int j8 = 0; j8 < 4; ++j8) {
          bf16x4 pk;
          pk[0] = f2bf(st[j8][0]); pk[1] = f2bf(st[j8][1]);
          pk[2] = f2bf(st[j8][2]); pk[3] = f2bf(st[j8][3]);
          *(bf16x4*)&Plds[wave][c][j8 * 16 + q4 * 4] = pk;
        }
        __builtin_amdgcn_s_setprio(1);
#pragma unroll
        for (int ks = 0; ks < 2; ++ks) {
          const bf16x8 pv = *(const bf16x8*)&Plds[wave][c][ks * 32 + q4 * 8];
#pragma unroll
          for (int dj = 0; dj < 8; ++dj) {
            const bf16x8 vv = *(const bf16x8*)
                &Vld[buf][((ks * 4 + q4) * 128 + dj * 16 + c) * 8];
            Ot[g][dj] = MFMA16(vv, pv, Ot[g][dj]);
          }
        }
        __builtin_amdgcn_s_setprio(0);
      }
      // no end-of-chunk sync: next iteration's vmcnt(0)+barrier covers it
    }

    if (!split) {
#pragma unroll
      for (int g = 0; g < 2; ++g) {
        const float inv = 1.0f / l_i[g];
        float* orow = out + ((size_t)b * Sq + q0 + g * 16 + c) * Eq + h * Dq;
#pragma unroll
        for (int dj = 0; dj < 8; ++dj) {
          float4 o;
          o.x = Ot[g][dj][0] * inv; o.y = Ot[g][dj][1] * inv;
          o.z = Ot[g][dj][2] * inv; o.w = Ot[g][dj][3] * inv;
          *(float4*)&orow[dj * 16 + q4 * 4] = o;
        }
      }
    } else {
      const int tix = (((b * Hq + h) * 8) + (qt - 8)) * 2 + sp;
#pragma unroll
      for (int g = 0; g < 2; ++g) {
        const int wrow = wave * 32 + g * 16 + c;
        float* prow = opart + ((size_t)tix * 128 + wrow) * 128;
#pragma unroll
        for (int dj = 0; dj < 8; ++dj) {
          float4 o;
          o.x = Ot[g][dj][0]; o.y = Ot[g][dj][1];
          o.z = Ot[g][dj][2]; o.w = Ot[g][dj][3];
          *(float4*)&prow[dj * 16 + q4 * 4] = o;
        }
        if (q4 == 0) {
          ml[((size_t)tix * 128 + wrow) * 2 + 0] = m_i[g];
          ml[((size_t)tix * 128 + wrow) * 2 + 1] = l_i[g];
        }
      }
    }
  }
}

// ---------------------------------------------------------------------------
// Kernel 4: combine the two split-K halves for qt>=8 tiles (verified).
// ---------------------------------------------------------------------------
__global__ __launch_bounds__(256) void attn_combine(
    const float* __restrict__ opart, const float* __restrict__ ml,
    float* __restrict__ out) {
  const int tile = blockIdx.x;
  const int qt = (tile & 7) + 8;
  const int hb = tile >> 3;
  const int h = hb & 15, b = hb >> 4;
  const int tid = threadIdx.x;
  const int r = tid >> 1;
  const int d0 = (tid & 1) * 64;
  const int t0 = tile * 2, t1 = t0 + 1;

  const float m0 = ml[((size_t)t0 * 128 + r) * 2 + 0];
  const float l0 = ml[((size_t)t0 * 128 + r) * 2 + 1];
  const float m1 = ml[((size_t)t1 * 128 + r) * 2 + 0];
  const float l1 = ml[((size_t)t1 * 128 + r) * 2 + 1];
  const float m = fmaxf(m0, m1);
  const float w0 = exp2f(m0 - m);
  const float w1 = exp2f(m1 - m);
  const float inv = 1.0f / (l0 * w0 + l1 * w1);
  const float s0 = w0 * inv, s1 = w1 * inv;

  const float* p0 = opart + ((size_t)t0 * 128 + r) * 128 + d0;
  const float* p1 = opart + ((size_t)t1 * 128 + r) * 128 + d0;
  float* orow = out + ((size_t)(b * Sq + qt * 128 + r)) * Eq + h * Dq + d0;
#pragma unroll
  for (int i = 0; i < 16; ++i) {
    float4 a = *(const float4*)&p0[i * 4];
    float4 bb = *(const float4*)&p1[i * 4];
    float4 o;
    o.x = a.x * s0 + bb.x * s1;
    o.y = a.y * s0 + bb.y * s1;
    o.z = a.z * s0 + bb.z * s1;
    o.w = a.w * s0 + bb.w * s1;
    *(float4*)&orow[i * 4] = o;
  }
}

// ---------------------------------------------------------------------------
extern "C" void kernel_launch(void* const* d_in, const int* in_sizes, int n_in,
                              void* d_out, int out_size, void* d_ws,
                              size_t ws_size, hipStream_t stream) {
  const float* x = (const float*)d_in[0];
  // d_in[1] = mask (causal tril) — implemented analytically, not read.
  const float* w = (const float*)d_in[2];
  float* out = (float*)d_out;

  const size_t nX = (size_t)Bq * Sq * Eq;         // 8,388,608
  const size_t nW = (size_t)Eq * N3E;             // 12,582,912
  const size_t perT = (size_t)Bq * Hq * Sq * Dq;  // 8,388,608

  bf16* xb = (bf16*)d_ws;
  bf16* wt = xb + nX;
  bf16* qws = wt + nW;
  bf16* kws = qws + perT;
  bf16* vtws = kws + perT;
  float2* tbl = (float2*)(vtws + perT);  // 2048*64 float2 = 1 MB
  float* wsend = (float*)(tbl + (size_t)Sq * 64);

  // Dedicated opart region (R10); fallback to aliasing if workspace small.
  const size_t nOpart = (size_t)512 * 128 * 128;      // 33.55 MB f32
  const size_t nMl = (size_t)512 * 128 * 2;           // 0.5 MB f32
  const size_t usedB = (size_t)((char*)wsend - (char*)d_ws);
  float* opart;
  if (ws_size >= usedB + (nOpart + nMl) * sizeof(float)) {
    opart = wsend;               // dedicated region (no aliasing)
  } else {
    opart = (float*)d_ws;        // fallback (aliases xb/wt)
  }
  float* ml = opart + nOpart;

  prep<<<5632, 256, 0, stream>>>(x, xb, w, wt, tbl);

  gemm_qkv<<<768, 512, 0, stream>>>(xb, wt, tbl, qws, kws, vtws);

  dim3 g3(16, 16, 2);  // 512 blocks; static split-K schedule
  attn_kernel<<<g3, 256, 0, stream>>>(qws, kws, vtws, out, opart, ml);

  attn_combine<<<256, 256, 0, stream>>>(opart, ml, out);
}